// Round 13
// baseline (1502.479 us; speedup 1.0000x reference)
//
#include <hip/hip_runtime.h>

#define T_LEN 2050
#define B_SZ 128
#define NCHUNK 33               // chunks of steps t=1..2049
#define NEMIS 65600             // emis blocks: (T_LEN*B_SZ)/4
#define HL2PI 0.91893853320467274178f

// ---------- wave-wide helpers (wave = 64 lanes) ----------
__device__ __forceinline__ float waveMax(float v) {
#pragma unroll
    for (int off = 32; off >= 1; off >>= 1)
        v = fmaxf(v, __shfl_xor(v, off, 64));
    return v;
}
__device__ __forceinline__ float waveSum(float v) {
#pragma unroll
    for (int off = 32; off >= 1; off >>= 1)
        v += __shfl_xor(v, off, 64);
    return v;
}
__device__ __forceinline__ void waveArgmax(float& v, int& idx) {
#pragma unroll
    for (int off = 32; off >= 1; off >>= 1) {
        float ov = __shfl_xor(v, off, 64);
        int   oi = __shfl_xor(idx, off, 64);
        if (ov > v || (ov == v && oi < idx)) { v = ov; idx = oi; }
    }
}
__device__ __forceinline__ void cfence() { asm volatile("" ::: "memory"); }

// DPP full-wave reductions (rounds 5-12 proven)
__device__ __forceinline__ float dppSumAll(float v) {
#define SSTEP(ctrl) { int t_ = __builtin_amdgcn_update_dpp(0, __float_as_int(v), ctrl, 0xf, 0xf, true); \
                      v = v + __int_as_float(t_); }
    SSTEP(0x111) SSTEP(0x112) SSTEP(0x114) SSTEP(0x118) SSTEP(0x142) SSTEP(0x143)
#undef SSTEP
    return __int_as_float(__builtin_amdgcn_readlane(__float_as_int(v), 63));
}
__device__ __forceinline__ float dppMaxAll(float v) {
#define MSTEP(ctrl) { int t_ = __builtin_amdgcn_update_dpp(__float_as_int(v), __float_as_int(v), ctrl, 0xf, 0xf, false); \
                      v = fmaxf(v, __int_as_float(t_)); }
    MSTEP(0x111) MSTEP(0x112) MSTEP(0x114) MSTEP(0x118) MSTEP(0x142) MSTEP(0x143)
#undef MSTEP
    return __int_as_float(__builtin_amdgcn_readlane(__float_as_int(v), 63));
}
// full-wave rotate right by 1: dst lane j <- src lane (j+1)&63  (DPP wave_ror:1)
__device__ __forceinline__ float ror1(float v) {
    int r = __builtin_amdgcn_update_dpp(__float_as_int(v), __float_as_int(v),
                                        0x13C, 0xf, 0xf, false);
    return __int_as_float(r);
}

// ===== emis (+ prep in last block): EXACT lp (round-2 proven bit-exact) -> buf[b][t][64], m_pre[b][t];
// block NEMIS computes log_softmax(log_A) -> lAg (column-major), log_softmax(log_pi) -> lpig =====
extern "C" __global__ __launch_bounds__(256)
void hmm_emis(const float* __restrict__ x,
              const float* __restrict__ means,
              const float* __restrict__ stds,
              const float* __restrict__ logA_in,
              const float* __restrict__ logpi_in,
              float* __restrict__ buf,
              float* __restrict__ m_pre,
              float* __restrict__ lAg,
              float* __restrict__ lpig)
{
    __shared__ float la[64 * 65];
    __shared__ float rowlse[64];

    if (blockIdx.x == NEMIS) {
        // ---- prep path (first wave only; rounds 1..12 proven exact op order) ----
        if (threadIdx.x >= 64) return;
        const int j = threadIdx.x;
#pragma unroll
        for (int k = 0; k < 64; ++k)
            la[k * 65 + j] = logA_in[k * 64 + j];
        cfence();
        {
            float m = -1e30f;
#pragma unroll
            for (int k = 0; k < 64; ++k) m = fmaxf(m, la[j * 65 + k]);
            float s = 0.f;
#pragma unroll
            for (int k = 0; k < 64; ++k) s += expf(la[j * 65 + k] - m);
            rowlse[j] = m + logf(s);
        }
        cfence();
        {
            float v = logpi_in[j];
            float m = waveMax(v);
            float s = waveSum(expf(v - m));
            lpig[j] = v - (m + logf(s));
        }
        float4* o = (float4*)lAg;
#pragma unroll
        for (int k = 0; k < 16; ++k) {
            float4 v;
            v.x = la[(4 * k + 0) * 65 + j] - rowlse[4 * k + 0];
            v.y = la[(4 * k + 1) * 65 + j] - rowlse[4 * k + 1];
            v.z = la[(4 * k + 2) * 65 + j] - rowlse[4 * k + 2];
            v.w = la[(4 * k + 3) * 65 + j] - rowlse[4 * k + 3];
            o[j * 16 + k] = v;
        }
        return;
    }

    // ---- emission path ----
    const int wid = blockIdx.x * 4 + (threadIdx.x >> 6);
    const int j = threadIdx.x & 63;
    const int t = wid >> 7;          // wid = t*128 + b
    const int b = wid & 127;

    const float* xt = x + ((size_t)b * T_LEN + t) * 6;
    float x0 = xt[0], x1 = xt[1], x2 = xt[2], x3 = xt[3];

    float mu0 = means[j * 6 + 0], mu1 = means[j * 6 + 1];
    float mu2 = means[j * 6 + 2], mu3 = means[j * 6 + 3];
    float sg0 = fmaxf(stds[j * 6 + 0], 0.f) + 0.1f;
    float sg1 = fmaxf(stds[j * 6 + 1], 0.f) + 0.1f;
    float sg2 = fmaxf(stds[j * 6 + 2], 0.f) + 0.1f;
    float sg3 = fmaxf(stds[j * 6 + 3], 0.f) + 0.1f;
    float ls0 = logf(sg0), ls1 = logf(sg1), ls2 = logf(sg2), ls3 = logf(sg3);

    float z0 = (x0 - mu0) / sg0, z1 = (x1 - mu1) / sg1;
    float z2 = (x2 - mu2) / sg2, z3 = (x3 - mu3) / sg3;
    float e0 = ((-0.5f * z0) * z0 - ls0) - HL2PI;
    float e1 = ((-0.5f * z1) * z1 - ls1) - HL2PI;
    float e2 = ((-0.5f * z2) * z2 - ls2) - HL2PI;
    float e3 = ((-0.5f * z3) * z3 - ls3) - HL2PI;
    float lp = ((e0 + e1) + e2) + e3;

    buf[((size_t)b * T_LEN + t) * 64 + j] = lp;
    float mm = waveMax(lp);
    if (j == 0) m_pre[(size_t)b * T_LEN + t] = mm;
}

// ===== main: single wave per chain; all-to-all broadcast via DPP wave rotation.
// Lane j accumulates over s: r holds d[(j+s)&63]; lAr[s] = lA[(j+s)&63][j] pre-gathered.
// blocks 0..127: forward -> out[b]; blocks 128..255: viterbi -> d over lp in buf, c_last =====
extern "C" __global__ __launch_bounds__(64, 1)
void hmm_main(const float* __restrict__ x,
              const float* __restrict__ means,
              const float* __restrict__ stds,
              const float* __restrict__ lAg,
              const float* __restrict__ lpig,
              float* __restrict__ out,
              float* __restrict__ buf,
              const float* __restrict__ m_pre,
              int* __restrict__ c_last)
{
    __shared__ __align__(16) float xs[12304];     // x[b] (forward half only)
    __shared__ __align__(16) float cbuf[4096];    // column staging for rotated gather

    const int j   = threadIdx.x;
    const int bid = blockIdx.x;
    const bool is_fwd = (bid < B_SZ);
    const int b = is_fwd ? bid : bid - B_SZ;

    float lpi = lpig[j];

    // stage my log_A column to LDS, then gather ROTATED: lAr[s] = lA[(j+s)&63][j]
    float lAr[64];
    {
        const float4* g = (const float4*)lAg;
        float4* cb4 = (float4*)(cbuf + j * 64);
#pragma unroll
        for (int k = 0; k < 16; ++k) cb4[k] = g[j * 16 + k];
        cfence();   // same-lane write->read, in-order DS
#pragma unroll
        for (int s = 0; s < 64; ++s)
            lAr[s] = cbuf[j * 64 + ((j + s) & 63)];
    }

    if (is_fwd) {
        {
            const float4* xg4 = (const float4*)(x + (size_t)b * T_LEN * 6);
            float4* xs4 = (float4*)xs;
            for (int i = j; i < 3075; i += 64) xs4[i] = xg4[i];
        }
        float mu0 = means[j * 6 + 0], mu1 = means[j * 6 + 1];
        float mu2 = means[j * 6 + 2], mu3 = means[j * 6 + 3];
        float sg0 = fmaxf(stds[j * 6 + 0], 0.f) + 0.1f;
        float sg1 = fmaxf(stds[j * 6 + 1], 0.f) + 0.1f;
        float sg2 = fmaxf(stds[j * 6 + 2], 0.f) + 0.1f;
        float sg3 = fmaxf(stds[j * 6 + 3], 0.f) + 0.1f;
        float ls0 = logf(sg0), ls1 = logf(sg1), ls2 = logf(sg2), ls3 = logf(sg3);
        float i0 = 1.f / sg0, i1 = 1.f / sg1, i2 = 1.f / sg2, i3 = 1.f / sg3;
        float cst = -(ls0 + ls1 + ls2 + ls3) - 4.f * HL2PI;

        float Acr[64];    // rotated A column: Acr[s] = A[(j+s)&63][j]
#pragma unroll
        for (int s = 0; s < 64; ++s) Acr[s] = __expf(lAr[s]);
        cfence();   // xs staged

        // t = 0 (round-12 math, unchanged)
        float z0 = (xs[0] - mu0) * i0, z1 = (xs[1] - mu1) * i1;
        float z2 = (xs[2] - mu2) * i2, z3 = (xs[3] - mu3) * i3;
        float a0 = (cst - 0.5f * (z0 * z0 + z1 * z1 + z2 * z2 + z3 * z3)) + lpi;
        float m0a = dppMaxAll(a0);
        float u = __expf(a0 - m0a);
        float s0 = dppSumAll(u);
        double acc = (double)(m0a + __logf(s0));
        u *= (1.0f / s0);

        const float* mp = m_pre + (size_t)b * T_LEN;
        float g0 = mp[1], g1 = mp[2], g2 = mp[3], g3 = mp[4];

#pragma unroll 1
        for (int t = 1; t < T_LEN; ++t) {
            float mm_c = g0; g0 = g1; g1 = g2; g2 = g3;
            int tp = t + 4; if (tp > T_LEN - 1) tp = T_LEN - 1;
            g3 = mp[tp];

            int o = t * 6;
            float y0 = xs[o], y1 = xs[o + 1], y2 = xs[o + 2], y3 = xs[o + 3];
            float w0 = (y0 - mu0) * i0, w1 = (y1 - mu1) * i1;
            float w2 = (y2 - mu2) * i2, w3 = (y3 - mu3) * i3;
            float lp = cst - 0.5f * (w0 * w0 + w1 * w1 + w2 * w2 + w3 * w3);
            float e_c = __expf(lp - mm_c);

            // q = sum_s u[(j+s)&63] * A[(j+s)&63][j]  via rotation broadcast
            float r = u;
            float q0 = 0.f, q1 = 0.f, q2 = 0.f, q3 = 0.f;
#pragma unroll
            for (int s = 0; s < 64; s += 4) {
                q0 = fmaf(r, Acr[s + 0], q0); r = ror1(r);
                q1 = fmaf(r, Acr[s + 1], q1); r = ror1(r);
                q2 = fmaf(r, Acr[s + 2], q2); r = ror1(r);
                q3 = fmaf(r, Acr[s + 3], q3);
                if (s + 4 < 64) r = ror1(r);
            }
            u = ((q0 + q1) + (q2 + q3)) * e_c;
            acc += (double)mm_c;
            if ((t & 3) == 0) {          // deferred renorm (rounds 9-12 proven)
                float ss = dppSumAll(u);
                acc += (double)__logf(ss);
                u *= (1.0f / ss);
            }
        }
        float sf = dppSumAll(u);
        acc += (double)__logf(sf);
        if (j == 0) out[b] = (float)acc;
    } else {
        // ---------------- VITERBI: rotation broadcast; exact lp from buf; in-place d ----------------
        float* bb = buf + (size_t)b * T_LEN * 64 + j;

        float dn = bb[0] + lpi;
        float l0 = bb[64], l1 = bb[128], l2 = bb[192], l3 = bb[256];
        bb[0] = dn;

#pragma unroll 1
        for (int t = 1; t < T_LEN; ++t) {
            float lp_c = l0; l0 = l1; l1 = l2; l2 = l3;
            int tp = t + 4; if (tp > T_LEN - 1) tp = T_LEN - 1;
            l3 = bb[(size_t)tp * 64];        // read t+4 before row t+4 is written

            // best = max_s( d[(j+s)&63] + lA[(j+s)&63][j] )  via rotation broadcast
            // (identical operand set as reference; fmax commutative/assoc -> bit-exact)
            float r = dn;
            float m0 = -3.4e38f, m1 = -3.4e38f, m2 = -3.4e38f, m3 = -3.4e38f;
#pragma unroll
            for (int s = 0; s < 64; s += 4) {
                m0 = fmaxf(m0, r + lAr[s + 0]); r = ror1(r);
                m1 = fmaxf(m1, r + lAr[s + 1]); r = ror1(r);
                m2 = fmaxf(m2, r + lAr[s + 2]); r = ror1(r);
                m3 = fmaxf(m3, r + lAr[s + 3]);
                if (s + 4 < 64) r = ror1(r);
            }
            dn = fmaxf(fmaxf(m0, m1), fmaxf(m2, m3)) + lp_c;

            bb[(size_t)t * 64] = dn;         // fire-and-forget global store
        }

        float vv = dn; int idx = j;
        waveArgmax(vv, idx);
        if (j == 0) c_last[b] = idx;
    }
}

// ===== psi recompute: contiguous (b,t) chunks for streaming locality =====
extern "C" __global__ __launch_bounds__(256)
void hmm_psi(const float* __restrict__ buf,
             const float* __restrict__ lAg,
             unsigned char* __restrict__ psi)
{
    __shared__ __align__(16) float sd[4][64];
    const int warp = threadIdx.x >> 6;
    const int j = threadIdx.x & 63;
    const int wid = blockIdx.x * 4 + warp;        // 0..8199

    float lA[64];
    {
        const float4* g = (const float4*)lAg;
#pragma unroll
        for (int k = 0; k < 16; ++k) {
            float4 v = g[j * 16 + k];
            lA[4 * k + 0] = v.x; lA[4 * k + 1] = v.y;
            lA[4 * k + 2] = v.z; lA[4 * k + 3] = v.w;
        }
    }
    const float4* dv = (const float4*)sd[warp];
    const int NP = 2049 * B_SZ;
    const int p0 = wid * 32;
    const int p1 = (p0 + 32 < NP) ? p0 + 32 : NP;

#pragma unroll 2
    for (int p = p0; p < p1; ++p) {
        // contiguous mapping: p = b*2049 + (t-1) -> sequential buf rows per wave
        const int b = p / 2049;
        const int t = p - b * 2049 + 1;
        float dval = buf[((size_t)b * T_LEN + (t - 1)) * 64 + j];
        sd[warp][j] = dval;    // same-wave in-order: reads below see it

        // round-5-verbatim argmax tracker (np.argmax first-occurrence semantics)
        float bv0 = -3.4e38f, bv1 = -3.4e38f, bv2 = -3.4e38f, bv3 = -3.4e38f;
        int bi0 = 0, bi1 = 1, bi2 = 2, bi3 = 3;
#pragma unroll
        for (int k = 0; k < 16; ++k) {
            float4 dd = dv[k];
            float v0 = dd.x + lA[4 * k + 0];
            float v1 = dd.y + lA[4 * k + 1];
            float v2 = dd.z + lA[4 * k + 2];
            float v3 = dd.w + lA[4 * k + 3];
            if (v0 > bv0) { bv0 = v0; bi0 = 4 * k + 0; }
            if (v1 > bv1) { bv1 = v1; bi1 = 4 * k + 1; }
            if (v2 > bv2) { bv2 = v2; bi2 = 4 * k + 2; }
            if (v3 > bv3) { bv3 = v3; bi3 = 4 * k + 3; }
        }
        float best = bv0; int bidx = bi0;
        if (bv1 > best || (bv1 == best && bi1 < bidx)) { best = bv1; bidx = bi1; }
        if (bv2 > best || (bv2 == best && bi2 < bidx)) { best = bv2; bidx = bi2; }
        if (bv3 > best || (bv3 == best && bi3 < bidx)) { best = bv3; bidx = bi3; }

        psi[((size_t)t * B_SZ + b) * 64 + j] = (unsigned char)bidx;
    }
}

// ===== per-chunk backpointer composition: wave per (b, g) =====
extern "C" __global__ __launch_bounds__(256)
void hmm_compose(const unsigned char* __restrict__ psi,
                 unsigned char* __restrict__ mt)
{
    const int w = blockIdx.x * 4 + (threadIdx.x >> 6);   // 0 .. 4223
    const int j = threadIdx.x & 63;
    const int g = w % NCHUNK;
    const int b = w / NCHUNK;
    const int e = (g < NCHUNK - 1) ? g * 64 + 64 : (T_LEN - 1);
    int M = j;
    for (int t = e; t >= g * 64 + 1; --t)
        M = psi[((size_t)t * B_SZ + b) * 64 + M];
    mt[((size_t)g * B_SZ + b) * 64 + j] = (unsigned char)M;
}

// ===== boundary walk + parallel chunk fill: block per batch =====
extern "C" __global__ __launch_bounds__(64, 1)
void hmm_fill(const unsigned char* __restrict__ psi,
              const unsigned char* __restrict__ mt,
              const int* __restrict__ c_last,
              float* __restrict__ out)
{
    __shared__ int sb[NCHUNK];       // sb[g] = state at t = 64*g
    const int b = blockIdx.x;
    const int g = threadIdx.x;
    const int cl = c_last[b];
    if (g == 0) {
        int cur = cl;
        for (int q = NCHUNK - 1; q >= 0; --q) {
            cur = mt[((size_t)q * B_SZ + b) * 64 + cur];
            sb[q] = cur;
        }
    }
    cfence();   // single wave, in-order DS
    float* oc = out + B_SZ + (size_t)b * T_LEN;
    if (g == NCHUNK) {
        oc[T_LEN - 1] = (float)cl;
    } else if (g < NCHUNK) {
        const int e = (g < NCHUNK - 1) ? g * 64 + 64 : (T_LEN - 1);
        int s = (g < NCHUNK - 1) ? sb[g + 1] : cl;
        for (int t = e; t >= g * 64 + 1; --t) {
            s = psi[((size_t)t * B_SZ + b) * 64 + s];
            oc[t - 1] = (float)s;
        }
    }
}

extern "C" void kernel_launch(void* const* d_in, const int* in_sizes, int n_in,
                              void* d_out, int out_size, void* d_ws, size_t ws_size,
                              hipStream_t stream)
{
    const float* x      = (const float*)d_in[0];
    const float* means  = (const float*)d_in[1];
    const float* stds   = (const float*)d_in[2];
    const float* logA   = (const float*)d_in[3];
    const float* logpi  = (const float*)d_in[4];
    float* out = (float*)d_out;

    // workspace: 84,255,488 B (proven to fit). m_pre overlaps the psi region
    // (consumed by hmm_main before hmm_psi writes psi).
    char* base = (char*)d_ws;
    float*         buf   = (float*)base;                                 // 67,174,400 (lp then d, in place)
    unsigned char* psi   = (unsigned char*)(base + 67174400);            // 16,793,600
    float*         m_pre = (float*)(base + 67174400);                    //  1,049,600 (dead after hmm_main)
    unsigned char* mt    = (unsigned char*)(base + 83968000);            //    270,336
    int*           cl    = (int*)(base + 84238336);                      //        512
    float*         lAg   = (float*)(base + 84238848);                    //     16,384
    float*         lpig  = (float*)(base + 84255232);                    //        256

    hipLaunchKernelGGL(hmm_emis, dim3(NEMIS + 1), dim3(256), 0, stream,
                       x, means, stds, logA, logpi, buf, m_pre, lAg, lpig);
    hipLaunchKernelGGL(hmm_main, dim3(2 * B_SZ), dim3(64), 0, stream,
                       x, means, stds, lAg, lpig, out, buf, m_pre, cl);
    hipLaunchKernelGGL(hmm_psi, dim3(2050), dim3(256), 0, stream, buf, lAg, psi);
    hipLaunchKernelGGL(hmm_compose, dim3((NCHUNK * B_SZ) / 4), dim3(256), 0, stream, psi, mt);
    hipLaunchKernelGGL(hmm_fill, dim3(B_SZ), dim3(64), 0, stream, psi, mt, cl, out);
}

// Round 14
// 1086.133 us; speedup vs baseline: 1.3833x; 1.3833x over previous
//
#include <hip/hip_runtime.h>

#define T_LEN 2050
#define B_SZ 128
#define NCHUNK 33               // chunks of steps t=1..2049
#define NEMIS 65600             // emis blocks: (T_LEN*B_SZ)/4
#define HL2PI 0.91893853320467274178f

// ---------- wave-wide helpers (wave = 64 lanes) ----------
__device__ __forceinline__ float waveMax(float v) {
#pragma unroll
    for (int off = 32; off >= 1; off >>= 1)
        v = fmaxf(v, __shfl_xor(v, off, 64));
    return v;
}
__device__ __forceinline__ float waveSum(float v) {
#pragma unroll
    for (int off = 32; off >= 1; off >>= 1)
        v += __shfl_xor(v, off, 64);
    return v;
}
__device__ __forceinline__ void waveArgmax(float& v, int& idx) {
#pragma unroll
    for (int off = 32; off >= 1; off >>= 1) {
        float ov = __shfl_xor(v, off, 64);
        int   oi = __shfl_xor(idx, off, 64);
        if (ov > v || (ov == v && oi < idx)) { v = ov; idx = oi; }
    }
}
__device__ __forceinline__ void cfence() { asm volatile("" ::: "memory"); }

// DPP full-wave reductions — row_* modes only (wave_* DPP is NOT supported on CDNA4:
// round-13 measured absmax 128 + slowdown from 0x13C wave_ror)
__device__ __forceinline__ float dppSumAll(float v) {
#define SSTEP(ctrl) { int t_ = __builtin_amdgcn_update_dpp(0, __float_as_int(v), ctrl, 0xf, 0xf, true); \
                      v = v + __int_as_float(t_); }
    SSTEP(0x111) SSTEP(0x112) SSTEP(0x114) SSTEP(0x118) SSTEP(0x142) SSTEP(0x143)
#undef SSTEP
    return __int_as_float(__builtin_amdgcn_readlane(__float_as_int(v), 63));
}
__device__ __forceinline__ float dppMaxAll(float v) {
#define MSTEP(ctrl) { int t_ = __builtin_amdgcn_update_dpp(__float_as_int(v), __float_as_int(v), ctrl, 0xf, 0xf, false); \
                      v = fmaxf(v, __int_as_float(t_)); }
    MSTEP(0x111) MSTEP(0x112) MSTEP(0x114) MSTEP(0x118) MSTEP(0x142) MSTEP(0x143)
#undef MSTEP
    return __int_as_float(__builtin_amdgcn_readlane(__float_as_int(v), 63));
}

// ===== emis (+ prep in last block): EXACT lp (round-2 proven bit-exact) -> buf[b][t][64], m_pre[b][t];
// block NEMIS computes log_softmax(log_A) -> lAg (column-major), log_softmax(log_pi) -> lpig =====
extern "C" __global__ __launch_bounds__(256)
void hmm_emis(const float* __restrict__ x,
              const float* __restrict__ means,
              const float* __restrict__ stds,
              const float* __restrict__ logA_in,
              const float* __restrict__ logpi_in,
              float* __restrict__ buf,
              float* __restrict__ m_pre,
              float* __restrict__ lAg,
              float* __restrict__ lpig)
{
    __shared__ float la[64 * 65];
    __shared__ float rowlse[64];

    if (blockIdx.x == NEMIS) {
        // ---- prep path (first wave only; rounds 1..12 proven exact op order) ----
        if (threadIdx.x >= 64) return;
        const int j = threadIdx.x;
#pragma unroll
        for (int k = 0; k < 64; ++k)
            la[k * 65 + j] = logA_in[k * 64 + j];
        cfence();
        {
            float m = -1e30f;
#pragma unroll
            for (int k = 0; k < 64; ++k) m = fmaxf(m, la[j * 65 + k]);
            float s = 0.f;
#pragma unroll
            for (int k = 0; k < 64; ++k) s += expf(la[j * 65 + k] - m);
            rowlse[j] = m + logf(s);
        }
        cfence();
        {
            float v = logpi_in[j];
            float m = waveMax(v);
            float s = waveSum(expf(v - m));
            lpig[j] = v - (m + logf(s));
        }
        float4* o = (float4*)lAg;
#pragma unroll
        for (int k = 0; k < 16; ++k) {
            float4 v;
            v.x = la[(4 * k + 0) * 65 + j] - rowlse[4 * k + 0];
            v.y = la[(4 * k + 1) * 65 + j] - rowlse[4 * k + 1];
            v.z = la[(4 * k + 2) * 65 + j] - rowlse[4 * k + 2];
            v.w = la[(4 * k + 3) * 65 + j] - rowlse[4 * k + 3];
            o[j * 16 + k] = v;
        }
        return;
    }

    // ---- emission path ----
    const int wid = blockIdx.x * 4 + (threadIdx.x >> 6);
    const int j = threadIdx.x & 63;
    const int t = wid >> 7;          // wid = t*128 + b
    const int b = wid & 127;

    const float* xt = x + ((size_t)b * T_LEN + t) * 6;
    float x0 = xt[0], x1 = xt[1], x2 = xt[2], x3 = xt[3];

    float mu0 = means[j * 6 + 0], mu1 = means[j * 6 + 1];
    float mu2 = means[j * 6 + 2], mu3 = means[j * 6 + 3];
    float sg0 = fmaxf(stds[j * 6 + 0], 0.f) + 0.1f;
    float sg1 = fmaxf(stds[j * 6 + 1], 0.f) + 0.1f;
    float sg2 = fmaxf(stds[j * 6 + 2], 0.f) + 0.1f;
    float sg3 = fmaxf(stds[j * 6 + 3], 0.f) + 0.1f;
    float ls0 = logf(sg0), ls1 = logf(sg1), ls2 = logf(sg2), ls3 = logf(sg3);

    float z0 = (x0 - mu0) / sg0, z1 = (x1 - mu1) / sg1;
    float z2 = (x2 - mu2) / sg2, z3 = (x3 - mu3) / sg3;
    float e0 = ((-0.5f * z0) * z0 - ls0) - HL2PI;
    float e1 = ((-0.5f * z1) * z1 - ls1) - HL2PI;
    float e2 = ((-0.5f * z2) * z2 - ls2) - HL2PI;
    float e3 = ((-0.5f * z3) * z3 - ls3) - HL2PI;
    float lp = ((e0 + e1) + e2) + e3;

    buf[((size_t)b * T_LEN + t) * 64 + j] = lp;
    float mm = waveMax(lp);
    if (j == 0) m_pre[(size_t)b * T_LEN + t] = mm;
}

// ===== main: single wave per chain, LDS broadcast + stripped chain (round-11/12 proven).
// Viterbi reduce uses v_max3-friendly trees (bit-exact: fmax is exactly assoc/comm).
// blocks 0..127: forward -> out[b]; blocks 128..255: viterbi -> d over lp in buf, c_last =====
extern "C" __global__ __launch_bounds__(64, 1)
void hmm_main(const float* __restrict__ x,
              const float* __restrict__ means,
              const float* __restrict__ stds,
              const float* __restrict__ lAg,
              const float* __restrict__ lpig,
              float* __restrict__ out,
              float* __restrict__ buf,
              const float* __restrict__ m_pre,
              int* __restrict__ c_last)
{
    __shared__ __align__(16) float xs[12304];     // x[b] (forward half only)
    __shared__ __align__(16) float pbuf[64];      // write-then-readback broadcast

    const int j   = threadIdx.x;
    const int bid = blockIdx.x;
    const bool is_fwd = (bid < B_SZ);
    const int b = is_fwd ? bid : bid - B_SZ;

    float lpi = lpig[j];
    const float4* pv = (const float4*)pbuf;

    if (is_fwd) {
        {
            const float4* xg4 = (const float4*)(x + (size_t)b * T_LEN * 6);
            float4* xs4 = (float4*)xs;
            for (int i = j; i < 3075; i += 64) xs4[i] = xg4[i];
        }
        float mu0 = means[j * 6 + 0], mu1 = means[j * 6 + 1];
        float mu2 = means[j * 6 + 2], mu3 = means[j * 6 + 3];
        float sg0 = fmaxf(stds[j * 6 + 0], 0.f) + 0.1f;
        float sg1 = fmaxf(stds[j * 6 + 1], 0.f) + 0.1f;
        float sg2 = fmaxf(stds[j * 6 + 2], 0.f) + 0.1f;
        float sg3 = fmaxf(stds[j * 6 + 3], 0.f) + 0.1f;
        float ls0 = logf(sg0), ls1 = logf(sg1), ls2 = logf(sg2), ls3 = logf(sg3);
        float i0 = 1.f / sg0, i1 = 1.f / sg1, i2 = 1.f / sg2, i3 = 1.f / sg3;
        float cst = -(ls0 + ls1 + ls2 + ls3) - 4.f * HL2PI;

        float Ac[64];
        {
            const float4* g = (const float4*)lAg;
#pragma unroll
            for (int k = 0; k < 16; ++k) {
                float4 v = g[j * 16 + k];
                Ac[4 * k + 0] = __expf(v.x); Ac[4 * k + 1] = __expf(v.y);
                Ac[4 * k + 2] = __expf(v.z); Ac[4 * k + 3] = __expf(v.w);
            }
        }
        cfence();   // xs staged (same-wave in-order DS)

        // t = 0
        float z0 = (xs[0] - mu0) * i0, z1 = (xs[1] - mu1) * i1;
        float z2 = (xs[2] - mu2) * i2, z3 = (xs[3] - mu3) * i3;
        float a0 = (cst - 0.5f * (z0 * z0 + z1 * z1 + z2 * z2 + z3 * z3)) + lpi;
        float m0a = dppMaxAll(a0);
        float u = __expf(a0 - m0a);
        float s0 = dppSumAll(u);
        double acc = (double)(m0a + __logf(s0));
        u *= (1.0f / s0);
        pbuf[j] = u;
        float4 rr[16];
#pragma unroll
        for (int k = 0; k < 16; ++k) rr[k] = pv[k];

        const float* mp = m_pre + (size_t)b * T_LEN;
        float g0 = mp[1], g1 = mp[2], g2 = mp[3], g3 = mp[4];

#pragma unroll 1
        for (int t = 1; t < T_LEN; ++t) {
            float mm_c = g0; g0 = g1; g1 = g2; g2 = g3;
            int tp = t + 4; if (tp > T_LEN - 1) tp = T_LEN - 1;
            g3 = mp[tp];

            int o = t * 6;
            float y0 = xs[o], y1 = xs[o + 1], y2 = xs[o + 2], y3 = xs[o + 3];
            float w0 = (y0 - mu0) * i0, w1 = (y1 - mu1) * i1;
            float w2 = (y2 - mu2) * i2, w3 = (y3 - mu3) * i3;
            float lp = cst - 0.5f * (w0 * w0 + w1 * w1 + w2 * w2 + w3 * w3);
            float e_c = __expf(lp - mm_c);

            float q0 = 0.f, q1 = 0.f, q2 = 0.f, q3 = 0.f;
#pragma unroll
            for (int k = 0; k < 16; ++k) {
                float4 pp = rr[k];
                q0 = fmaf(pp.x, Ac[4 * k + 0], q0);
                q1 = fmaf(pp.y, Ac[4 * k + 1], q1);
                q2 = fmaf(pp.z, Ac[4 * k + 2], q2);
                q3 = fmaf(pp.w, Ac[4 * k + 3], q3);
            }
            u = ((q0 + q1) + (q2 + q3)) * e_c;
            acc += (double)mm_c;
            if ((t & 3) == 0) {          // deferred renorm (rounds 9-12 proven)
                float ss = dppSumAll(u);
                acc += (double)__logf(ss);
                u *= (1.0f / ss);
            }

            pbuf[j] = u;
#pragma unroll
            for (int k = 0; k < 16; ++k) rr[k] = pv[k];
        }
        float sf = dppSumAll(u);
        acc += (double)__logf(sf);
        if (j == 0) out[b] = (float)acc;
    } else {
        float lA[64];
        {
            const float4* g = (const float4*)lAg;
#pragma unroll
            for (int k = 0; k < 16; ++k) {
                float4 v = g[j * 16 + k];
                lA[4 * k + 0] = v.x; lA[4 * k + 1] = v.y;
                lA[4 * k + 2] = v.z; lA[4 * k + 3] = v.w;
            }
        }
        float* bb = buf + (size_t)b * T_LEN * 64 + j;

        float dn = bb[0] + lpi;
        float l0 = bb[64], l1 = bb[128], l2 = bb[192], l3 = bb[256];
        bb[0] = dn;
        pbuf[j] = dn;
        float4 rr[16];
#pragma unroll
        for (int k = 0; k < 16; ++k) rr[k] = pv[k];

#pragma unroll 1
        for (int t = 1; t < T_LEN; ++t) {
            float lp_c = l0; l0 = l1; l1 = l2; l2 = l3;
            int tp = t + 4; if (tp > T_LEN - 1) tp = T_LEN - 1;
            l3 = bb[(size_t)tp * 64];        // read t+4 before row t+4 is written

            // reduce best = max_i(d[i]+lA[i][j]) — v_max3 trees, 4 accumulators
            // (fmax exactly assoc/comm -> bit-identical to any tree shape)
            float m0 = -3.4e38f, m1 = -3.4e38f, m2 = -3.4e38f, m3 = -3.4e38f;
#pragma unroll
            for (int k = 0; k < 8; ++k) {
                float4 da = rr[2 * k];
                float4 db = rr[2 * k + 1];
                float t0 = da.x + lA[8 * k + 0];
                float t1 = da.y + lA[8 * k + 1];
                float t2 = da.z + lA[8 * k + 2];
                float t3 = da.w + lA[8 * k + 3];
                float t4 = db.x + lA[8 * k + 4];
                float t5 = db.y + lA[8 * k + 5];
                float t6 = db.z + lA[8 * k + 6];
                float t7 = db.w + lA[8 * k + 7];
                m0 = fmaxf(m0, fmaxf(t0, t1));   // -> v_max3_f32
                m1 = fmaxf(m1, fmaxf(t2, t3));
                m2 = fmaxf(m2, fmaxf(t4, t5));
                m3 = fmaxf(m3, fmaxf(t6, t7));
            }
            dn = fmaxf(fmaxf(m0, m1), fmaxf(m2, m3)) + lp_c;

            bb[(size_t)t * 64] = dn;         // fire-and-forget global store
            pbuf[j] = dn;
#pragma unroll
            for (int k = 0; k < 16; ++k) rr[k] = pv[k];
        }

        float vv = dn; int idx = j;
        waveArgmax(vv, idx);
        if (j == 0) c_last[b] = idx;
    }
}

// ===== psi recompute: contiguous (b,t) chunks for streaming locality =====
extern "C" __global__ __launch_bounds__(256)
void hmm_psi(const float* __restrict__ buf,
             const float* __restrict__ lAg,
             unsigned char* __restrict__ psi)
{
    __shared__ __align__(16) float sd[4][64];
    const int warp = threadIdx.x >> 6;
    const int j = threadIdx.x & 63;
    const int wid = blockIdx.x * 4 + warp;        // 0..8199

    float lA[64];
    {
        const float4* g = (const float4*)lAg;
#pragma unroll
        for (int k = 0; k < 16; ++k) {
            float4 v = g[j * 16 + k];
            lA[4 * k + 0] = v.x; lA[4 * k + 1] = v.y;
            lA[4 * k + 2] = v.z; lA[4 * k + 3] = v.w;
        }
    }
    const float4* dv = (const float4*)sd[warp];
    const int NP = 2049 * B_SZ;
    const int p0 = wid * 32;
    const int p1 = (p0 + 32 < NP) ? p0 + 32 : NP;

#pragma unroll 2
    for (int p = p0; p < p1; ++p) {
        // contiguous mapping: p = b*2049 + (t-1) -> sequential buf rows per wave
        const int b = p / 2049;
        const int t = p - b * 2049 + 1;
        float dval = buf[((size_t)b * T_LEN + (t - 1)) * 64 + j];
        sd[warp][j] = dval;    // same-wave in-order: reads below see it

        // round-5-verbatim argmax tracker (np.argmax first-occurrence semantics)
        float bv0 = -3.4e38f, bv1 = -3.4e38f, bv2 = -3.4e38f, bv3 = -3.4e38f;
        int bi0 = 0, bi1 = 1, bi2 = 2, bi3 = 3;
#pragma unroll
        for (int k = 0; k < 16; ++k) {
            float4 dd = dv[k];
            float v0 = dd.x + lA[4 * k + 0];
            float v1 = dd.y + lA[4 * k + 1];
            float v2 = dd.z + lA[4 * k + 2];
            float v3 = dd.w + lA[4 * k + 3];
            if (v0 > bv0) { bv0 = v0; bi0 = 4 * k + 0; }
            if (v1 > bv1) { bv1 = v1; bi1 = 4 * k + 1; }
            if (v2 > bv2) { bv2 = v2; bi2 = 4 * k + 2; }
            if (v3 > bv3) { bv3 = v3; bi3 = 4 * k + 3; }
        }
        float best = bv0; int bidx = bi0;
        if (bv1 > best || (bv1 == best && bi1 < bidx)) { best = bv1; bidx = bi1; }
        if (bv2 > best || (bv2 == best && bi2 < bidx)) { best = bv2; bidx = bi2; }
        if (bv3 > best || (bv3 == best && bi3 < bidx)) { best = bv3; bidx = bi3; }

        psi[((size_t)t * B_SZ + b) * 64 + j] = (unsigned char)bidx;
    }
}

// ===== per-chunk backpointer composition: wave per (b, g) =====
extern "C" __global__ __launch_bounds__(256)
void hmm_compose(const unsigned char* __restrict__ psi,
                 unsigned char* __restrict__ mt)
{
    const int w = blockIdx.x * 4 + (threadIdx.x >> 6);   // 0 .. 4223
    const int j = threadIdx.x & 63;
    const int g = w % NCHUNK;
    const int b = w / NCHUNK;
    const int e = (g < NCHUNK - 1) ? g * 64 + 64 : (T_LEN - 1);
    int M = j;
    for (int t = e; t >= g * 64 + 1; --t)
        M = psi[((size_t)t * B_SZ + b) * 64 + M];
    mt[((size_t)g * B_SZ + b) * 64 + j] = (unsigned char)M;
}

// ===== boundary walk + parallel chunk fill: block per batch =====
extern "C" __global__ __launch_bounds__(64, 1)
void hmm_fill(const unsigned char* __restrict__ psi,
              const unsigned char* __restrict__ mt,
              const int* __restrict__ c_last,
              float* __restrict__ out)
{
    __shared__ int sb[NCHUNK];       // sb[g] = state at t = 64*g
    const int b = blockIdx.x;
    const int g = threadIdx.x;
    const int cl = c_last[b];
    if (g == 0) {
        int cur = cl;
        for (int q = NCHUNK - 1; q >= 0; --q) {
            cur = mt[((size_t)q * B_SZ + b) * 64 + cur];
            sb[q] = cur;
        }
    }
    cfence();   // single wave, in-order DS
    float* oc = out + B_SZ + (size_t)b * T_LEN;
    if (g == NCHUNK) {
        oc[T_LEN - 1] = (float)cl;
    } else if (g < NCHUNK) {
        const int e = (g < NCHUNK - 1) ? g * 64 + 64 : (T_LEN - 1);
        int s = (g < NCHUNK - 1) ? sb[g + 1] : cl;
        for (int t = e; t >= g * 64 + 1; --t) {
            s = psi[((size_t)t * B_SZ + b) * 64 + s];
            oc[t - 1] = (float)s;
        }
    }
}

extern "C" void kernel_launch(void* const* d_in, const int* in_sizes, int n_in,
                              void* d_out, int out_size, void* d_ws, size_t ws_size,
                              hipStream_t stream)
{
    const float* x      = (const float*)d_in[0];
    const float* means  = (const float*)d_in[1];
    const float* stds   = (const float*)d_in[2];
    const float* logA   = (const float*)d_in[3];
    const float* logpi  = (const float*)d_in[4];
    float* out = (float*)d_out;

    // workspace: 84,255,488 B (proven to fit). m_pre overlaps the psi region
    // (consumed by hmm_main before hmm_psi writes psi).
    char* base = (char*)d_ws;
    float*         buf   = (float*)base;                                 // 67,174,400 (lp then d, in place)
    unsigned char* psi   = (unsigned char*)(base + 67174400);            // 16,793,600
    float*         m_pre = (float*)(base + 67174400);                    //  1,049,600 (dead after hmm_main)
    unsigned char* mt    = (unsigned char*)(base + 83968000);            //    270,336
    int*           cl    = (int*)(base + 84238336);                      //        512
    float*         lAg   = (float*)(base + 84238848);                    //     16,384
    float*         lpig  = (float*)(base + 84255232);                    //        256

    hipLaunchKernelGGL(hmm_emis, dim3(NEMIS + 1), dim3(256), 0, stream,
                       x, means, stds, logA, logpi, buf, m_pre, lAg, lpig);
    hipLaunchKernelGGL(hmm_main, dim3(2 * B_SZ), dim3(64), 0, stream,
                       x, means, stds, lAg, lpig, out, buf, m_pre, cl);
    hipLaunchKernelGGL(hmm_psi, dim3(2050), dim3(256), 0, stream, buf, lAg, psi);
    hipLaunchKernelGGL(hmm_compose, dim3((NCHUNK * B_SZ) / 4), dim3(256), 0, stream, psi, mt);
    hipLaunchKernelGGL(hmm_fill, dim3(B_SZ), dim3(64), 0, stream, psi, mt, cl, out);
}

// Round 15
// 1069.729 us; speedup vs baseline: 1.4045x; 1.0153x over previous
//
#include <hip/hip_runtime.h>

#define T_LEN 2050
#define B_SZ 128
#define NCHUNK 33               // chunks of steps t=1..2049
#define NEMIS 65600             // emis blocks: (T_LEN*B_SZ)/4
#define HL2PI 0.91893853320467274178f

// ---------- wave-wide helpers (wave = 64 lanes) ----------
__device__ __forceinline__ float waveMax(float v) {
#pragma unroll
    for (int off = 32; off >= 1; off >>= 1)
        v = fmaxf(v, __shfl_xor(v, off, 64));
    return v;
}
__device__ __forceinline__ float waveSum(float v) {
#pragma unroll
    for (int off = 32; off >= 1; off >>= 1)
        v += __shfl_xor(v, off, 64);
    return v;
}
__device__ __forceinline__ void waveArgmax(float& v, int& idx) {
#pragma unroll
    for (int off = 32; off >= 1; off >>= 1) {
        float ov = __shfl_xor(v, off, 64);
        int   oi = __shfl_xor(idx, off, 64);
        if (ov > v || (ov == v && oi < idx)) { v = ov; idx = oi; }
    }
}
__device__ __forceinline__ void cfence() { asm volatile("" ::: "memory"); }

// DPP full-wave reductions — row_* modes only (wave_* DPP broken on CDNA4: round-13 evidence)
__device__ __forceinline__ float dppSumAll(float v) {
#define SSTEP(ctrl) { int t_ = __builtin_amdgcn_update_dpp(0, __float_as_int(v), ctrl, 0xf, 0xf, true); \
                      v = v + __int_as_float(t_); }
    SSTEP(0x111) SSTEP(0x112) SSTEP(0x114) SSTEP(0x118) SSTEP(0x142) SSTEP(0x143)
#undef SSTEP
    return __int_as_float(__builtin_amdgcn_readlane(__float_as_int(v), 63));
}
__device__ __forceinline__ float dppMaxAll(float v) {
#define MSTEP(ctrl) { int t_ = __builtin_amdgcn_update_dpp(__float_as_int(v), __float_as_int(v), ctrl, 0xf, 0xf, false); \
                      v = fmaxf(v, __int_as_float(t_)); }
    MSTEP(0x111) MSTEP(0x112) MSTEP(0x114) MSTEP(0x118) MSTEP(0x142) MSTEP(0x143)
#undef MSTEP
    return __int_as_float(__builtin_amdgcn_readlane(__float_as_int(v), 63));
}

// ===== emis (+ prep in last block): EXACT lp (round-2 proven bit-exact) -> buf[b][t][64], m_pre[b][t];
// block NEMIS computes log_softmax(log_A) -> lAg (column-major), log_softmax(log_pi) -> lpig =====
extern "C" __global__ __launch_bounds__(256)
void hmm_emis(const float* __restrict__ x,
              const float* __restrict__ means,
              const float* __restrict__ stds,
              const float* __restrict__ logA_in,
              const float* __restrict__ logpi_in,
              float* __restrict__ buf,
              float* __restrict__ m_pre,
              float* __restrict__ lAg,
              float* __restrict__ lpig)
{
    __shared__ float la[64 * 65];
    __shared__ float rowlse[64];

    if (blockIdx.x == NEMIS) {
        // ---- prep path (first wave only; rounds 1..12 proven exact op order) ----
        if (threadIdx.x >= 64) return;
        const int j = threadIdx.x;
#pragma unroll
        for (int k = 0; k < 64; ++k)
            la[k * 65 + j] = logA_in[k * 64 + j];
        cfence();
        {
            float m = -1e30f;
#pragma unroll
            for (int k = 0; k < 64; ++k) m = fmaxf(m, la[j * 65 + k]);
            float s = 0.f;
#pragma unroll
            for (int k = 0; k < 64; ++k) s += expf(la[j * 65 + k] - m);
            rowlse[j] = m + logf(s);
        }
        cfence();
        {
            float v = logpi_in[j];
            float m = waveMax(v);
            float s = waveSum(expf(v - m));
            lpig[j] = v - (m + logf(s));
        }
        float4* o = (float4*)lAg;
#pragma unroll
        for (int k = 0; k < 16; ++k) {
            float4 v;
            v.x = la[(4 * k + 0) * 65 + j] - rowlse[4 * k + 0];
            v.y = la[(4 * k + 1) * 65 + j] - rowlse[4 * k + 1];
            v.z = la[(4 * k + 2) * 65 + j] - rowlse[4 * k + 2];
            v.w = la[(4 * k + 3) * 65 + j] - rowlse[4 * k + 3];
            o[j * 16 + k] = v;
        }
        return;
    }

    // ---- emission path ----
    const int wid = blockIdx.x * 4 + (threadIdx.x >> 6);
    const int j = threadIdx.x & 63;
    const int t = wid >> 7;          // wid = t*128 + b
    const int b = wid & 127;

    const float* xt = x + ((size_t)b * T_LEN + t) * 6;
    float x0 = xt[0], x1 = xt[1], x2 = xt[2], x3 = xt[3];

    float mu0 = means[j * 6 + 0], mu1 = means[j * 6 + 1];
    float mu2 = means[j * 6 + 2], mu3 = means[j * 6 + 3];
    float sg0 = fmaxf(stds[j * 6 + 0], 0.f) + 0.1f;
    float sg1 = fmaxf(stds[j * 6 + 1], 0.f) + 0.1f;
    float sg2 = fmaxf(stds[j * 6 + 2], 0.f) + 0.1f;
    float sg3 = fmaxf(stds[j * 6 + 3], 0.f) + 0.1f;
    float ls0 = logf(sg0), ls1 = logf(sg1), ls2 = logf(sg2), ls3 = logf(sg3);

    float z0 = (x0 - mu0) / sg0, z1 = (x1 - mu1) / sg1;
    float z2 = (x2 - mu2) / sg2, z3 = (x3 - mu3) / sg3;
    float e0 = ((-0.5f * z0) * z0 - ls0) - HL2PI;
    float e1 = ((-0.5f * z1) * z1 - ls1) - HL2PI;
    float e2 = ((-0.5f * z2) * z2 - ls2) - HL2PI;
    float e3 = ((-0.5f * z3) * z3 - ls3) - HL2PI;
    float lp = ((e0 + e1) + e2) + e3;

    buf[((size_t)b * T_LEN + t) * 64 + j] = lp;
    float mm = waveMax(lp);
    if (j == 0) m_pre[(size_t)b * T_LEN + t] = mm;
}

// ===== main: single wave per chain, LDS broadcast + stripped chain (rounds 11/12 measured optimum).
// blocks 0..127: forward -> out[b]; blocks 128..255: viterbi -> d over lp in buf, c_last =====
extern "C" __global__ __launch_bounds__(64, 1)
void hmm_main(const float* __restrict__ x,
              const float* __restrict__ means,
              const float* __restrict__ stds,
              const float* __restrict__ lAg,
              const float* __restrict__ lpig,
              float* __restrict__ out,
              float* __restrict__ buf,
              const float* __restrict__ m_pre,
              int* __restrict__ c_last)
{
    __shared__ __align__(16) float xs[12304];     // x[b] (forward half only)
    __shared__ __align__(16) float pbuf[64];      // write-then-readback broadcast

    const int j   = threadIdx.x;
    const int bid = blockIdx.x;
    const bool is_fwd = (bid < B_SZ);
    const int b = is_fwd ? bid : bid - B_SZ;

    float lpi = lpig[j];
    const float4* pv = (const float4*)pbuf;

    if (is_fwd) {
        {
            const float4* xg4 = (const float4*)(x + (size_t)b * T_LEN * 6);
            float4* xs4 = (float4*)xs;
            for (int i = j; i < 3075; i += 64) xs4[i] = xg4[i];
        }
        float mu0 = means[j * 6 + 0], mu1 = means[j * 6 + 1];
        float mu2 = means[j * 6 + 2], mu3 = means[j * 6 + 3];
        float sg0 = fmaxf(stds[j * 6 + 0], 0.f) + 0.1f;
        float sg1 = fmaxf(stds[j * 6 + 1], 0.f) + 0.1f;
        float sg2 = fmaxf(stds[j * 6 + 2], 0.f) + 0.1f;
        float sg3 = fmaxf(stds[j * 6 + 3], 0.f) + 0.1f;
        float ls0 = logf(sg0), ls1 = logf(sg1), ls2 = logf(sg2), ls3 = logf(sg3);
        float i0 = 1.f / sg0, i1 = 1.f / sg1, i2 = 1.f / sg2, i3 = 1.f / sg3;
        float cst = -(ls0 + ls1 + ls2 + ls3) - 4.f * HL2PI;

        float Ac[64];
        {
            const float4* g = (const float4*)lAg;
#pragma unroll
            for (int k = 0; k < 16; ++k) {
                float4 v = g[j * 16 + k];
                Ac[4 * k + 0] = __expf(v.x); Ac[4 * k + 1] = __expf(v.y);
                Ac[4 * k + 2] = __expf(v.z); Ac[4 * k + 3] = __expf(v.w);
            }
        }
        cfence();   // xs staged (same-wave in-order DS)

        // t = 0
        float z0 = (xs[0] - mu0) * i0, z1 = (xs[1] - mu1) * i1;
        float z2 = (xs[2] - mu2) * i2, z3 = (xs[3] - mu3) * i3;
        float a0 = (cst - 0.5f * (z0 * z0 + z1 * z1 + z2 * z2 + z3 * z3)) + lpi;
        float m0a = dppMaxAll(a0);
        float u = __expf(a0 - m0a);
        float s0 = dppSumAll(u);
        double acc = (double)(m0a + __logf(s0));
        u *= (1.0f / s0);
        pbuf[j] = u;
        float4 rr[16];
#pragma unroll
        for (int k = 0; k < 16; ++k) rr[k] = pv[k];

        const float* mp = m_pre + (size_t)b * T_LEN;
        float g0 = mp[1], g1 = mp[2], g2 = mp[3], g3 = mp[4];

#pragma unroll 1
        for (int t = 1; t < T_LEN; ++t) {
            float mm_c = g0; g0 = g1; g1 = g2; g2 = g3;
            int tp = t + 4; if (tp > T_LEN - 1) tp = T_LEN - 1;
            g3 = mp[tp];

            int o = t * 6;
            float y0 = xs[o], y1 = xs[o + 1], y2 = xs[o + 2], y3 = xs[o + 3];
            float w0 = (y0 - mu0) * i0, w1 = (y1 - mu1) * i1;
            float w2 = (y2 - mu2) * i2, w3 = (y3 - mu3) * i3;
            float lp = cst - 0.5f * (w0 * w0 + w1 * w1 + w2 * w2 + w3 * w3);
            float e_c = __expf(lp - mm_c);

            float q0 = 0.f, q1 = 0.f, q2 = 0.f, q3 = 0.f;
#pragma unroll
            for (int k = 0; k < 16; ++k) {
                float4 pp = rr[k];
                q0 = fmaf(pp.x, Ac[4 * k + 0], q0);
                q1 = fmaf(pp.y, Ac[4 * k + 1], q1);
                q2 = fmaf(pp.z, Ac[4 * k + 2], q2);
                q3 = fmaf(pp.w, Ac[4 * k + 3], q3);
            }
            u = ((q0 + q1) + (q2 + q3)) * e_c;
            acc += (double)mm_c;
            if ((t & 3) == 0) {          // deferred renorm (rounds 9-12 proven)
                float ss = dppSumAll(u);
                acc += (double)__logf(ss);
                u *= (1.0f / ss);
            }

            pbuf[j] = u;
#pragma unroll
            for (int k = 0; k < 16; ++k) rr[k] = pv[k];
        }
        float sf = dppSumAll(u);
        acc += (double)__logf(sf);
        if (j == 0) out[b] = (float)acc;
    } else {
        float lA[64];
        {
            const float4* g = (const float4*)lAg;
#pragma unroll
            for (int k = 0; k < 16; ++k) {
                float4 v = g[j * 16 + k];
                lA[4 * k + 0] = v.x; lA[4 * k + 1] = v.y;
                lA[4 * k + 2] = v.z; lA[4 * k + 3] = v.w;
            }
        }
        float* bb = buf + (size_t)b * T_LEN * 64 + j;

        float dn = bb[0] + lpi;
        float l0 = bb[64], l1 = bb[128], l2 = bb[192], l3 = bb[256];
        bb[0] = dn;
        pbuf[j] = dn;
        float4 rr[16];
#pragma unroll
        for (int k = 0; k < 16; ++k) rr[k] = pv[k];

#pragma unroll 1
        for (int t = 1; t < T_LEN; ++t) {
            float lp_c = l0; l0 = l1; l1 = l2; l2 = l3;
            int tp = t + 4; if (tp > T_LEN - 1) tp = T_LEN - 1;
            l3 = bb[(size_t)tp * 64];        // read t+4 before row t+4 is written

            // reduce best = max_i(d[i]+lA[i][j]) (4 independent chains; fmax assoc: bit-exact)
            float m0 = -3.4e38f, m1 = -3.4e38f, m2 = -3.4e38f, m3 = -3.4e38f;
#pragma unroll
            for (int k = 0; k < 16; ++k) {
                float4 dd = rr[k];
                m0 = fmaxf(m0, dd.x + lA[4 * k + 0]);
                m1 = fmaxf(m1, dd.y + lA[4 * k + 1]);
                m2 = fmaxf(m2, dd.z + lA[4 * k + 2]);
                m3 = fmaxf(m3, dd.w + lA[4 * k + 3]);
            }
            dn = fmaxf(fmaxf(m0, m1), fmaxf(m2, m3)) + lp_c;

            bb[(size_t)t * 64] = dn;         // fire-and-forget global store
            pbuf[j] = dn;
#pragma unroll
            for (int k = 0; k < 16; ++k) rr[k] = pv[k];
        }

        float vv = dn; int idx = j;
        waveArgmax(vv, idx);
        if (j == 0) c_last[b] = idx;
    }
}

// ===== psi recompute: contiguous (b,t) chunks for streaming locality =====
extern "C" __global__ __launch_bounds__(256)
void hmm_psi(const float* __restrict__ buf,
             const float* __restrict__ lAg,
             unsigned char* __restrict__ psi)
{
    __shared__ __align__(16) float sd[4][64];
    const int warp = threadIdx.x >> 6;
    const int j = threadIdx.x & 63;
    const int wid = blockIdx.x * 4 + warp;        // 0..8199

    float lA[64];
    {
        const float4* g = (const float4*)lAg;
#pragma unroll
        for (int k = 0; k < 16; ++k) {
            float4 v = g[j * 16 + k];
            lA[4 * k + 0] = v.x; lA[4 * k + 1] = v.y;
            lA[4 * k + 2] = v.z; lA[4 * k + 3] = v.w;
        }
    }
    const float4* dv = (const float4*)sd[warp];
    const int NP = 2049 * B_SZ;
    const int p0 = wid * 32;
    const int p1 = (p0 + 32 < NP) ? p0 + 32 : NP;

#pragma unroll 2
    for (int p = p0; p < p1; ++p) {
        // contiguous mapping: p = b*2049 + (t-1) -> sequential buf rows per wave
        const int b = p / 2049;
        const int t = p - b * 2049 + 1;
        float dval = buf[((size_t)b * T_LEN + (t - 1)) * 64 + j];
        sd[warp][j] = dval;    // same-wave in-order: reads below see it

        // round-5-verbatim argmax tracker (np.argmax first-occurrence semantics)
        float bv0 = -3.4e38f, bv1 = -3.4e38f, bv2 = -3.4e38f, bv3 = -3.4e38f;
        int bi0 = 0, bi1 = 1, bi2 = 2, bi3 = 3;
#pragma unroll
        for (int k = 0; k < 16; ++k) {
            float4 dd = dv[k];
            float v0 = dd.x + lA[4 * k + 0];
            float v1 = dd.y + lA[4 * k + 1];
            float v2 = dd.z + lA[4 * k + 2];
            float v3 = dd.w + lA[4 * k + 3];
            if (v0 > bv0) { bv0 = v0; bi0 = 4 * k + 0; }
            if (v1 > bv1) { bv1 = v1; bi1 = 4 * k + 1; }
            if (v2 > bv2) { bv2 = v2; bi2 = 4 * k + 2; }
            if (v3 > bv3) { bv3 = v3; bi3 = 4 * k + 3; }
        }
        float best = bv0; int bidx = bi0;
        if (bv1 > best || (bv1 == best && bi1 < bidx)) { best = bv1; bidx = bi1; }
        if (bv2 > best || (bv2 == best && bi2 < bidx)) { best = bv2; bidx = bi2; }
        if (bv3 > best || (bv3 == best && bi3 < bidx)) { best = bv3; bidx = bi3; }

        psi[((size_t)t * B_SZ + b) * 64 + j] = (unsigned char)bidx;
    }
}

// ===== per-chunk backpointer composition: wave per (b, g) =====
extern "C" __global__ __launch_bounds__(256)
void hmm_compose(const unsigned char* __restrict__ psi,
                 unsigned char* __restrict__ mt)
{
    const int w = blockIdx.x * 4 + (threadIdx.x >> 6);   // 0 .. 4223
    const int j = threadIdx.x & 63;
    const int g = w % NCHUNK;
    const int b = w / NCHUNK;
    const int e = (g < NCHUNK - 1) ? g * 64 + 64 : (T_LEN - 1);
    int M = j;
    for (int t = e; t >= g * 64 + 1; --t)
        M = psi[((size_t)t * B_SZ + b) * 64 + M];
    mt[((size_t)g * B_SZ + b) * 64 + j] = (unsigned char)M;
}

// ===== boundary walk + parallel chunk fill: block per batch =====
extern "C" __global__ __launch_bounds__(64, 1)
void hmm_fill(const unsigned char* __restrict__ psi,
              const unsigned char* __restrict__ mt,
              const int* __restrict__ c_last,
              float* __restrict__ out)
{
    __shared__ int sb[NCHUNK];       // sb[g] = state at t = 64*g
    const int b = blockIdx.x;
    const int g = threadIdx.x;
    const int cl = c_last[b];
    if (g == 0) {
        int cur = cl;
        for (int q = NCHUNK - 1; q >= 0; --q) {
            cur = mt[((size_t)q * B_SZ + b) * 64 + cur];
            sb[q] = cur;
        }
    }
    cfence();   // single wave, in-order DS
    float* oc = out + B_SZ + (size_t)b * T_LEN;
    if (g == NCHUNK) {
        oc[T_LEN - 1] = (float)cl;
    } else if (g < NCHUNK) {
        const int e = (g < NCHUNK - 1) ? g * 64 + 64 : (T_LEN - 1);
        int s = (g < NCHUNK - 1) ? sb[g + 1] : cl;
        for (int t = e; t >= g * 64 + 1; --t) {
            s = psi[((size_t)t * B_SZ + b) * 64 + s];
            oc[t - 1] = (float)s;
        }
    }
}

extern "C" void kernel_launch(void* const* d_in, const int* in_sizes, int n_in,
                              void* d_out, int out_size, void* d_ws, size_t ws_size,
                              hipStream_t stream)
{
    const float* x      = (const float*)d_in[0];
    const float* means  = (const float*)d_in[1];
    const float* stds   = (const float*)d_in[2];
    const float* logA   = (const float*)d_in[3];
    const float* logpi  = (const float*)d_in[4];
    float* out = (float*)d_out;

    // workspace: 84,255,488 B (proven to fit). m_pre overlaps the psi region
    // (consumed by hmm_main before hmm_psi writes psi).
    char* base = (char*)d_ws;
    float*         buf   = (float*)base;                                 // 67,174,400 (lp then d, in place)
    unsigned char* psi   = (unsigned char*)(base + 67174400);            // 16,793,600
    float*         m_pre = (float*)(base + 67174400);                    //  1,049,600 (dead after hmm_main)
    unsigned char* mt    = (unsigned char*)(base + 83968000);            //    270,336
    int*           cl    = (int*)(base + 84238336);                      //        512
    float*         lAg   = (float*)(base + 84238848);                    //     16,384
    float*         lpig  = (float*)(base + 84255232);                    //        256

    hipLaunchKernelGGL(hmm_emis, dim3(NEMIS + 1), dim3(256), 0, stream,
                       x, means, stds, logA, logpi, buf, m_pre, lAg, lpig);
    hipLaunchKernelGGL(hmm_main, dim3(2 * B_SZ), dim3(64), 0, stream,
                       x, means, stds, lAg, lpig, out, buf, m_pre, cl);
    hipLaunchKernelGGL(hmm_psi, dim3(2050), dim3(256), 0, stream, buf, lAg, psi);
    hipLaunchKernelGGL(hmm_compose, dim3((NCHUNK * B_SZ) / 4), dim3(256), 0, stream, psi, mt);
    hipLaunchKernelGGL(hmm_fill, dim3(B_SZ), dim3(64), 0, stream, psi, mt, cl, out);
}